// Round 16
// baseline (115.344 us; speedup 1.0000x reference)
//
#include <hip/hip_runtime.h>
#include <hip/hip_bf16.h>

#define EPSV 1e-5f

typedef __attribute__((ext_vector_type(4))) float f32x4;
typedef __attribute__((ext_vector_type(8))) short bf16x8;
typedef unsigned short u16;
typedef unsigned int u32;

#define AS1(p) ((const __attribute__((address_space(1))) void*)(p))
#define AS3(p) ((__attribute__((address_space(3))) void*)(p))

__device__ __forceinline__ float bf2f(u16 u) {
    union { u32 i; float f; } x; x.i = ((u32)u) << 16; return x.f;
}
__device__ __forceinline__ u16 f2bf(float f) {
    __hip_bfloat16 h = __float2bfloat16(f);
    return *reinterpret_cast<u16*>(&h);
}

// ---------------------------------------------------------------------------
// Fused prep: weight conversions + 3x3 reorgs + zbuf. grid 833.
//   bz < 512   : w1/w3 fp32->bf16
//   512..575   : wOffP [64][2304] (rows >=18 zero)
//   576..831   : wb2p  [256][2304] (k*256+c layout for deform GEMM A)
//   bz == 832  : zbuf zero-fill
// ---------------------------------------------------------------------------
__global__ __launch_bounds__(256) void prep_all(
    const float* __restrict__ w1, const float* __restrict__ w3,
    const float* __restrict__ w_off, const float* __restrict__ w2,
    u16* __restrict__ wb1, u16* __restrict__ wb3,
    u16* __restrict__ wOffP, u16* __restrict__ wb2p,
    u16* __restrict__ zbuf)
{
    const int bz  = blockIdx.x;
    const int tid = threadIdx.x;
    if (bz < 512) {
        int i = bz * 256 + tid;
        const float* src; u16* dst; int j;
        if (i < 65536) { src = w1; dst = wb1; j = i; }
        else           { src = w3; dst = wb3; j = i - 65536; }
        float4 v = ((const float4*)src)[j];
        ushort4 o;
        o.x = f2bf(v.x); o.y = f2bf(v.y); o.z = f2bf(v.z); o.w = f2bf(v.w);
        ((ushort4*)dst)[j] = o;
        return;
    }
    const int bz1 = bz - 512;
    if (bz1 == 320) { ((u32*)zbuf)[tid] = 0; return; }
    if (bz1 < 64) {
#pragma unroll
        for (int k = 0; k < 9; k++) {
            float v = (bz1 < 18) ? w_off[((size_t)(bz1 * 256 + tid)) * 9 + k] : 0.f;
            wOffP[(size_t)bz1 * 2304 + k * 256 + tid] = f2bf(v);
        }
        return;
    }
    const int o = bz1 - 64;           // 0..255
#pragma unroll
    for (int k = 0; k < 9; k++) {
        wb2p[(size_t)o * 2304 + k * 256 + tid] =
            f2bf(w2[((size_t)(o * 256 + tid)) * 9 + k]);
    }
}

// ---------------------------------------------------------------------------
// x [2][1024][4096] fp32  ->  xbT [8192][1024] bf16
// ---------------------------------------------------------------------------
__global__ __launch_bounds__(256) void cvt_x_T(const float* __restrict__ x,
                                               u16* __restrict__ xbT) {
    __shared__ u16 tile[64][72];
    const int tid = threadIdx.x;
    const int hw0 = blockIdx.x << 6;
    const int c0  = blockIdx.y << 6;
    const int b   = blockIdx.z;
    const int cl  = tid >> 4;
    const int hwl = (tid & 15) << 2;
#pragma unroll
    for (int i = 0; i < 4; i++) {
        const int c = cl + i * 16;
        float4 v = *(const float4*)(x + (((size_t)(b * 1024 + c0 + c)) << 12) + hw0 + hwl);
        tile[hwl + 0][c] = f2bf(v.x);
        tile[hwl + 1][c] = f2bf(v.y);
        tile[hwl + 2][c] = f2bf(v.z);
        tile[hwl + 3][c] = f2bf(v.w);
    }
    __syncthreads();
    const int hw  = tid >> 2;
    const int seg = tid & 3;
    u16* dst = xbT + ((size_t)(b * 4096 + hw0 + hw)) * 1024 + c0 + seg * 16;
    const u16* src = &tile[hw][seg * 16];
#pragma unroll
    for (int q = 0; q < 2; q++)
        *(uint4*)(dst + q * 8) = *(const uint4*)(src + q * 8);
}

// ---------------------------------------------------------------------------
// Pipelined MFMA GEMM (64x128 tile, BK=32, 2-deep dbuf, counted vmcnt).
// MODE 1: BN+ReLU -> bf16 outT[8192][M] (stride 256), swizzled LDS transpose
// MODE 2: BN + resid + ReLU -> fp32 out [2][M][4096]
// MODE 3: raw bf16 partial -> P[blockIdx.z][M][8192] (split-K; BN in reduce)
// ---------------------------------------------------------------------------
#define MFMA8(ASP, BSP)                                                          \
    do {                                                                         \
        bf16x8 a0 = *(const bf16x8*)(ASP);                                       \
        bf16x8 a1 = *(const bf16x8*)((ASP) + 512);                               \
        bf16x8 b0 = *(const bf16x8*)(BSP);                                       \
        bf16x8 b1 = *(const bf16x8*)((BSP) + 512);                               \
        bf16x8 b2 = *(const bf16x8*)((BSP) + 1024);                              \
        bf16x8 b3 = *(const bf16x8*)((BSP) + 1536);                              \
        acc[0][0] = __builtin_amdgcn_mfma_f32_16x16x32_bf16(a0, b0, acc[0][0], 0, 0, 0); \
        acc[0][1] = __builtin_amdgcn_mfma_f32_16x16x32_bf16(a0, b1, acc[0][1], 0, 0, 0); \
        acc[0][2] = __builtin_amdgcn_mfma_f32_16x16x32_bf16(a0, b2, acc[0][2], 0, 0, 0); \
        acc[0][3] = __builtin_amdgcn_mfma_f32_16x16x32_bf16(a0, b3, acc[0][3], 0, 0, 0); \
        acc[1][0] = __builtin_amdgcn_mfma_f32_16x16x32_bf16(a1, b0, acc[1][0], 0, 0, 0); \
        acc[1][1] = __builtin_amdgcn_mfma_f32_16x16x32_bf16(a1, b1, acc[1][1], 0, 0, 0); \
        acc[1][2] = __builtin_amdgcn_mfma_f32_16x16x32_bf16(a1, b2, acc[1][2], 0, 0, 0); \
        acc[1][3] = __builtin_amdgcn_mfma_f32_16x16x32_bf16(a1, b3, acc[1][3], 0, 0, 0); \
    } while (0)

#define WAIT_BAR()                                  \
    do {                                            \
        asm volatile("s_waitcnt vmcnt(3)" ::: "memory"); \
        __builtin_amdgcn_s_barrier();               \
        __builtin_amdgcn_sched_barrier(0);          \
    } while (0)

#define POST_BAR()                                  \
    do {                                            \
        __builtin_amdgcn_s_barrier();               \
        __builtin_amdgcn_sched_barrier(0);          \
    } while (0)

template<int MODE>
__global__ __launch_bounds__(256) void gemm_bn(
    const u16* __restrict__ A, const u16* __restrict__ BT,
    const float* __restrict__ g, const float* __restrict__ bb,
    const float* __restrict__ m, const float* __restrict__ v,
    const float* __restrict__ resid, void* __restrict__ out, int K, int Ksub)
{
    extern __shared__ char sm[];

    const int tid  = threadIdx.x;
    const int lane = tid & 63;
    const int wid  = tid >> 6;
    const int n0 = blockIdx.x << 7;
    const int m0 = blockIdx.y << 6;
    const int kBase = blockIdx.z * Ksub;
    const int wr = wid >> 1, wc = wid & 1;
    const int lr = lane & 15, kg = lane >> 4;

    f32x4 acc[2][4] = {};

    const int arow = tid >> 2, aseg = (tid & 3) << 3;
    const u16* aG  = A  + (size_t)(m0 + arow) * K + kBase + aseg;
    const u16* bG0 = BT + (size_t)(n0 + arow) * K + kBase + aseg;
    const u16* bG1 = BT + (size_t)(n0 + 64 + arow) * K + kBase + aseg;

    char* ldsA0  = sm + wid * 1024;
    char* ldsA1  = sm + 4096  + wid * 1024;
    char* ldsB00 = sm + 8192  + wid * 1024;
    char* ldsB01 = sm + 12288 + wid * 1024;
    char* ldsB10 = sm + 16384 + wid * 1024;
    char* ldsB11 = sm + 20480 + wid * 1024;

    const u16* Asp0 = (const u16*)(sm)         + (wr * 32 + lr) * 32 + kg * 8;
    const u16* Asp1 = (const u16*)(sm + 4096)  + (wr * 32 + lr) * 32 + kg * 8;
    const u16* Bsp0 = (const u16*)(sm + 8192)  + (wc * 64 + lr) * 32 + kg * 8;
    const u16* Bsp1 = (const u16*)(sm + 16384) + (wc * 64 + lr) * 32 + kg * 8;

    // BN params preloaded + fenced BEFORE the pipeline (in-loop VMEM == staging)
    float sc[2][4], tc[2][4];
    if (MODE != 3) {
#pragma unroll
        for (int mm = 0; mm < 2; mm++)
#pragma unroll
            for (int r = 0; r < 4; r++) {
                const int o = m0 + wr * 32 + mm * 16 + kg * 4 + r;
                const float s = g[o] * rsqrtf(v[o] + EPSV);
                sc[mm][r] = s;
                tc[mm][r] = bb[o] - m[o] * s;
            }
    }
    asm volatile("s_waitcnt vmcnt(0) lgkmcnt(0)" ::: "memory");
    __builtin_amdgcn_sched_barrier(0);

#define ISSUE_G(LA, LB0, LB1, kt)                                                  \
    do {                                                                           \
        __builtin_amdgcn_global_load_lds(AS1(aG + (kt)),  AS3(LA),  16, 0, 0);     \
        __builtin_amdgcn_global_load_lds(AS1(bG0 + (kt)), AS3(LB0), 16, 0, 0);     \
        __builtin_amdgcn_global_load_lds(AS1(bG1 + (kt)), AS3(LB1), 16, 0, 0);     \
    } while (0)

    const int nT = Ksub >> 5;
    ISSUE_G(ldsA0, ldsB00, ldsB01, 0);
    ISSUE_G(ldsA1, ldsB10, ldsB11, 32);

    for (int t = 0; t < nT; t += 2) {
        WAIT_BAR();
        MFMA8(Asp0, Bsp0);
        POST_BAR();
        { const int kn = (t + 2 < nT ? t + 2 : t) << 5;
          ISSUE_G(ldsA0, ldsB00, ldsB01, kn); }
        WAIT_BAR();
        MFMA8(Asp1, Bsp1);
        POST_BAR();
        { const int kn = (t + 3 < nT ? t + 3 : t + 1) << 5;
          ISSUE_G(ldsA1, ldsB10, ldsB11, kn); }
    }
#undef ISSUE_G

    if (MODE == 1) {
        u32* T32 = (u32*)(sm + 24576);
#pragma unroll
        for (int mm = 0; mm < 2; mm++) {
            const int ol = wr * 32 + mm * 16 + kg * 4;
            const int cw0 = ol >> 1;
#pragma unroll
            for (int j = 0; j < 4; j++) {
                const int nl = wc * 64 + j * 16 + lr;
                const int sw = (nl >> 3) & 3;
                float v0 = acc[mm][j][0] * sc[mm][0] + tc[mm][0];
                float v1 = acc[mm][j][1] * sc[mm][1] + tc[mm][1];
                float v2 = acc[mm][j][2] * sc[mm][2] + tc[mm][2];
                float v3 = acc[mm][j][3] * sc[mm][3] + tc[mm][3];
                v0 = v0 > 0.f ? v0 : 0.f; v1 = v1 > 0.f ? v1 : 0.f;
                v2 = v2 > 0.f ? v2 : 0.f; v3 = v3 > 0.f ? v3 : 0.f;
                uint2 pw;
                pw.x = (u32)f2bf(v0) | ((u32)f2bf(v1) << 16);
                pw.y = (u32)f2bf(v2) | ((u32)f2bf(v3) << 16);
                *(uint2*)&T32[nl * 36 + (cw0 ^ (sw << 2))] = pw;
            }
        }
        __syncthreads();
        const int nl = tid >> 1, half = tid & 1;
        const int sw = (nl >> 3) & 3;
        u16* dst = (u16*)out + (size_t)(n0 + nl) * 256 + m0 + half * 32;
#pragma unroll
        for (int q = 0; q < 4; q++) {
            uint4 val = *(const uint4*)&T32[nl * 36 + ((half * 16 + q * 4) ^ (sw << 2))];
            *(uint4*)(dst + q * 8) = val;
        }
    } else if (MODE == 2) {
        float* T = (float*)(sm + 24576);   // [64][132]
#pragma unroll
        for (int mm = 0; mm < 2; mm++) {
            const int ol = wr * 32 + mm * 16 + kg * 4;
#pragma unroll
            for (int j = 0; j < 4; j++) {
                const int nl = wc * 64 + j * 16 + lr;
#pragma unroll
                for (int r = 0; r < 4; r++)
                    T[(ol + r) * 132 + nl] = acc[mm][j][r] * sc[mm][r] + tc[mm][r];
            }
        }
        __syncthreads();
        float* O = (float*)out;
        for (int idx = tid; idx < 2048; idx += 256) {
            const int ol  = idx >> 5;
            const int nl4 = (idx & 31) << 2;
            const int n = n0 + nl4;
            const size_t gidx = ((size_t)(n >> 12) << 22) + ((size_t)(m0 + ol) << 12) + (n & 4095);
            float4 rv = *(const float4*)(resid + gidx);
            float4 ov;
            ov.x = T[ol * 132 + nl4 + 0] + rv.x;
            ov.y = T[ol * 132 + nl4 + 1] + rv.y;
            ov.z = T[ol * 132 + nl4 + 2] + rv.z;
            ov.w = T[ol * 132 + nl4 + 3] + rv.w;
            ov.x = ov.x > 0.f ? ov.x : 0.f;
            ov.y = ov.y > 0.f ? ov.y : 0.f;
            ov.z = ov.z > 0.f ? ov.z : 0.f;
            ov.w = ov.w > 0.f ? ov.w : 0.f;
            *(float4*)(O + gidx) = ov;
        }
    } else {
        // MODE 3: bf16 partials; drain pipeline loads first (LDS reuse hazard)
        asm volatile("s_waitcnt vmcnt(0)" ::: "memory");
        u16* P = (u16*)out + (size_t)blockIdx.z * 2097152;
#pragma unroll
        for (int mm = 0; mm < 2; mm++)
#pragma unroll
            for (int r = 0; r < 4; r++) {
                const int o = m0 + wr * 32 + mm * 16 + kg * 4 + r;
#pragma unroll
                for (int j = 0; j < 4; j++) {
                    const int n = n0 + wc * 64 + j * 16 + lr;
                    P[((size_t)o << 13) + n] = f2bf(acc[mm][j][r]);
                }
            }
    }
}

// ---------------------------------------------------------------------------
// Offset conv: split-K x6 implicit-im2col MFMA GEMM, 2-deep pipeline.
// ---------------------------------------------------------------------------
__global__ __launch_bounds__(256) void gemm_off(
    const u16* __restrict__ A,      // [64][2304] (rows >=18 zero)
    const u16* __restrict__ out1T,  // [8192][256]
    const u16* __restrict__ zbuf,
    float* __restrict__ offsP)      // [6][2][18][4096]
{
    __shared__ char sm[24576];

    const int tid  = threadIdx.x;
    const int lane = tid & 63;
    const int wid  = tid >> 6;
    const int n0 = blockIdx.x << 7;
    const int kz = blockIdx.y;
    const int wr = wid >> 1, wc = wid & 1;
    const int lr = lane & 15, kg = lane >> 4;

    f32x4 acc[2][4] = {};

    const int arow = tid >> 2, aseg = (tid & 3) << 3;
    const u16* aG = A + (size_t)arow * 2304 + aseg;
    const int nB0 = n0 + arow, nB1 = n0 + 64 + arow;
    const int y0r = (nB0 & 4095) >> 6, x0r = nB0 & 63;
    const int y1r = (nB1 & 4095) >> 6, x1r = nB1 & 63;

    char* ldsA0  = sm + wid * 1024;
    char* ldsA1  = sm + 4096  + wid * 1024;
    char* ldsB00 = sm + 8192  + wid * 1024;
    char* ldsB01 = sm + 12288 + wid * 1024;
    char* ldsB10 = sm + 16384 + wid * 1024;
    char* ldsB11 = sm + 20480 + wid * 1024;

    const u16* Asp0 = (const u16*)(sm)         + (wr * 32 + lr) * 32 + kg * 8;
    const u16* Asp1 = (const u16*)(sm + 4096)  + (wr * 32 + lr) * 32 + kg * 8;
    const u16* Bsp0 = (const u16*)(sm + 8192)  + (wc * 64 + lr) * 32 + kg * 8;
    const u16* Bsp1 = (const u16*)(sm + 16384) + (wc * 64 + lr) * 32 + kg * 8;

#define ISSUE_O(LA, LB0, LB1, kt)                                                  \
    do {                                                                           \
        const int tap = (kt) >> 8, c0 = (kt) & 255;                                \
        const int dy = tap / 3 - 1, dx = tap % 3 - 1;                              \
        const int sh = dy * 64 + dx;                                               \
        const bool vv0 = ((unsigned)(y0r + dy) < 64u) && ((unsigned)(x0r + dx) < 64u); \
        const bool vv1 = ((unsigned)(y1r + dy) < 64u) && ((unsigned)(x1r + dx) < 64u); \
        const u16* s0 = vv0 ? out1T + (size_t)(nB0 + sh) * 256 + c0 + aseg : zbuf + aseg; \
        const u16* s1 = vv1 ? out1T + (size_t)(nB1 + sh) * 256 + c0 + aseg : zbuf + aseg; \
        __builtin_amdgcn_global_load_lds(AS1(aG + (kt)), AS3(LA),  16, 0, 0);      \
        __builtin_amdgcn_global_load_lds(AS1(s0),        AS3(LB0), 16, 0, 0);      \
        __builtin_amdgcn_global_load_lds(AS1(s1),        AS3(LB1), 16, 0, 0);      \
    } while (0)

    const int kBase = kz * 384;
    ISSUE_O(ldsA0, ldsB00, ldsB01, kBase);
    ISSUE_O(ldsA1, ldsB10, ldsB11, kBase + 32);

    for (int t = 0; t < 12; t += 2) {
        WAIT_BAR();
        MFMA8(Asp0, Bsp0);
        POST_BAR();
        { const int kn = kBase + ((t + 2 < 12 ? t + 2 : t) << 5);
          ISSUE_O(ldsA0, ldsB00, ldsB01, kn); }
        WAIT_BAR();
        MFMA8(Asp1, Bsp1);
        POST_BAR();
        { const int kn = kBase + ((t + 3 < 12 ? t + 3 : t + 1) << 5);
          ISSUE_O(ldsA1, ldsB10, ldsB11, kn); }
    }
#undef ISSUE_O

    asm volatile("s_waitcnt vmcnt(0)" ::: "memory");

#pragma unroll
    for (int mm = 0; mm < 2; mm++)
#pragma unroll
        for (int r = 0; r < 4; r++) {
            const int o = wr * 32 + mm * 16 + kg * 4 + r;
            if (o < 18) {
#pragma unroll
                for (int j = 0; j < 4; j++) {
                    const int n = n0 + wc * 64 + j * 16 + lr;
                    offsP[(size_t)kz * 147456 +
                          (((size_t)((n >> 12) * 18 + o)) << 12) + (n & 4095)] =
                        acc[mm][j][r];
                }
            }
        }
}

// ---------------------------------------------------------------------------
// Deformable im2col: ST[n][k*256+c] bf16. One wave per sample point, lanes =
// 128 channels (u32 = 2 bf16). Offset partial-sum (x6) + bias folded into
// the geometry pass. Grid (64 h, 2 b, 2 c-half), 256 threads.
// ---------------------------------------------------------------------------
__global__ __launch_bounds__(256) void sample_k(
    const u16* __restrict__ out1T,  // [8192][256]
    const float* __restrict__ offsP,// [6][2][18][4096]
    const float* __restrict__ b_off,
    u16* __restrict__ ST)           // [8192][2304]
{
    __shared__ int4   s_ofs[576];
    __shared__ float4 s_w[576];

    const int h  = blockIdx.x;
    const int b  = blockIdx.y;
    const int cs = blockIdx.z << 7;
    const int tid = threadIdx.x;

    for (int p = tid; p < 576; p += 256) {
        const int k = p >> 6;
        const int w = p & 63;
        const size_t iy = (((size_t)(b * 18 + 2 * k)) << 12) + (h << 6) + w;
        float dy = b_off[2 * k], dx = b_off[2 * k + 1];
#pragma unroll
        for (int kzz = 0; kzz < 6; kzz++) {
            dy += offsP[(size_t)kzz * 147456 + iy];
            dx += offsP[(size_t)kzz * 147456 + iy + 4096];
        }
        const float py = (float)h + (float)(k / 3 - 1) + dy;
        const float px = (float)w + (float)(k % 3 - 1) + dx;
        const float y0f = floorf(py), x0f = floorf(px);
        const int y0 = (int)y0f, x0 = (int)x0f;
        const float wy1 = py - y0f, wx1 = px - x0f;
        const float wy0 = 1.f - wy1, wx0 = 1.f - wx1;
        const int y1 = y0 + 1, x1 = x0 + 1;
        const bool vy0 = (y0 >= 0) && (y0 < 64);
        const bool vy1 = (y1 >= 0) && (y1 < 64);
        const bool vx0 = (x0 >= 0) && (x0 < 64);
        const bool vx1 = (x1 >= 0) && (x1 < 64);
        const int cy0 = min(max(y0, 0), 63), cy1 = min(max(y1, 0), 63);
        const int cx0 = min(max(x0, 0), 63), cx1 = min(max(x1, 0), 63);
        int4 o4; float4 w4;
        o4.x = (cy0 << 6) + cx0;  w4.x = wy0 * wx0 * ((vy0 && vx0) ? 1.f : 0.f);
        o4.y = (cy0 << 6) + cx1;  w4.y = wy0 * wx1 * ((vy0 && vx1) ? 1.f : 0.f);
        o4.z = (cy1 << 6) + cx0;  w4.z = wy1 * wx0 * ((vy1 && vx0) ? 1.f : 0.f);
        o4.w = (cy1 << 6) + cx1;  w4.w = wy1 * wx1 * ((vy1 && vx1) ? 1.f : 0.f);
        s_ofs[p] = o4; s_w[p] = w4;
    }
    __syncthreads();

    const int wv   = tid >> 6;
    const int lane = tid & 63;
    const int cl   = cs + lane * 2;
    const u16* base = out1T + (((size_t)b) << 12) * 256 + cl;
    for (int p = wv; p < 576; p += 4) {
        const int k = p >> 6;
        const int w = p & 63;
        const int4   o4 = s_ofs[p];
        const float4 w4 = s_w[p];
        const u32 u0 = *(const u32*)(base + (size_t)o4.x * 256);
        const u32 u1 = *(const u32*)(base + (size_t)o4.y * 256);
        const u32 u2 = *(const u32*)(base + (size_t)o4.z * 256);
        const u32 u3 = *(const u32*)(base + (size_t)o4.w * 256);
        const float f0 = w4.x * bf2f((u16)(u0 & 0xffff)) + w4.y * bf2f((u16)(u1 & 0xffff))
                       + w4.z * bf2f((u16)(u2 & 0xffff)) + w4.w * bf2f((u16)(u3 & 0xffff));
        const float f1 = w4.x * bf2f((u16)(u0 >> 16)) + w4.y * bf2f((u16)(u1 >> 16))
                       + w4.z * bf2f((u16)(u2 >> 16)) + w4.w * bf2f((u16)(u3 >> 16));
        const u32 ov = (u32)f2bf(f0) | ((u32)f2bf(f1) << 16);
        *(u32*)(ST + ((size_t)(b * 4096 + h * 64 + w)) * 2304 + k * 256 + cl) = ov;
    }
}

// ---------------------------------------------------------------------------
// Split-K reduce for the deform GEMM: o2T[n][m] = relu(bn(P0+P1)).
// P is bf16; accumulate in fp32.
// ---------------------------------------------------------------------------
__global__ __launch_bounds__(256) void reduce_bn(
    const u16* __restrict__ P,      // [2][256][8192] bf16
    const float* __restrict__ g, const float* __restrict__ bb,
    const float* __restrict__ m, const float* __restrict__ v,
    u16* __restrict__ o2T)          // [8192][256]
{
    __shared__ u16 tile[64][72];
    const int tid = threadIdx.x;
    const int n0 = blockIdx.x << 6;
    const int m0 = blockIdx.y << 6;

    const int ml = tid >> 2;
    const int ns = (tid & 3) << 4;
    const int o = m0 + ml;
    const float s = g[o] * rsqrtf(v[o] + EPSV);
    const float tcv = bb[o] - m[o] * s;
    const size_t base = ((size_t)o << 13) + n0 + ns;
#pragma unroll
    for (int qq = 0; qq < 2; qq++) {
        bf16x8 a = *(const bf16x8*)(P + base + qq * 8);
        bf16x8 b = *(const bf16x8*)(P + 2097152 + base + qq * 8);
#pragma unroll
        for (int i = 0; i < 8; i++) {
            float f = (bf2f((u16)a[i]) + bf2f((u16)b[i])) * s + tcv;
            f = f > 0.f ? f : 0.f;
            tile[ns + qq * 8 + i][ml] = f2bf(f);
        }
    }
    __syncthreads();
    const int nl = tid >> 2, seg = tid & 3;
    u16* dst = o2T + (size_t)(n0 + nl) * 256 + m0 + seg * 16;
    const u16* src = &tile[nl][seg * 16];
#pragma unroll
    for (int qq = 0; qq < 2; qq++)
        *(uint4*)(dst + qq * 8) = *(const uint4*)(src + qq * 8);
}

// ---------------------------------------------------------------------------
extern "C" void kernel_launch(void* const* d_in, const int* in_sizes, int n_in,
                              void* d_out, int out_size, void* d_ws, size_t ws_size,
                              hipStream_t stream) {
    const float* x     = (const float*)d_in[0];
    const float* w1    = (const float*)d_in[1];
    const float* g1    = (const float*)d_in[2];
    const float* b1    = (const float*)d_in[3];
    const float* m1    = (const float*)d_in[4];
    const float* v1    = (const float*)d_in[5];
    const float* w_off = (const float*)d_in[6];
    const float* b_off = (const float*)d_in[7];
    const float* w2    = (const float*)d_in[8];
    const float* g2    = (const float*)d_in[9];
    const float* b2    = (const float*)d_in[10];
    const float* m2    = (const float*)d_in[11];
    const float* v2    = (const float*)d_in[12];
    const float* w3    = (const float*)d_in[13];
    const float* g3    = (const float*)d_in[14];
    const float* b3    = (const float*)d_in[15];
    const float* m3    = (const float*)d_in[16];
    const float* v3    = (const float*)d_in[17];
    float* out = (float*)d_out;

    char* ws = (char*)d_ws;
    u16*  xbT   = (u16*)ws;   ws += (size_t)8192 * 1024 * 2;
    u16*  wb1   = (u16*)ws;   ws += (size_t)256 * 1024 * 2;
    u16*  wb3   = (u16*)ws;   ws += (size_t)1024 * 256 * 2;
    u16*  wOffP = (u16*)ws;   ws += (size_t)64 * 2304 * 2;
    u16*  wb2p  = (u16*)ws;   ws += (size_t)256 * 2304 * 2;
    u16*  zbuf  = (u16*)ws;   ws += (size_t)512 * 2;
    u16*  out1T = (u16*)ws;   ws += (size_t)8192 * 256 * 2;
    float* offsP = (float*)ws; ws += (size_t)6 * 147456 * 4;
    u16*  ST    = (u16*)ws;   ws += (size_t)8192 * 2304 * 2;   // 37.7 MB
    u16*  o2T   = (u16*)ws;   ws += (size_t)8192 * 256 * 2;
    u16*  P     = (u16*)ws;   ws += (size_t)2 * 2097152 * 2;   // 8.4 MB bf16

    prep_all<<<dim3(833), 256, 0, stream>>>(w1, w3, w_off, w2,
                                            wb1, wb3, wOffP, wb2p, zbuf);
    cvt_x_T<<<dim3(64, 16, 2), 256, 0, stream>>>(x, xbT);

    // Stage 1: conv1x1 + BN1 + ReLU -> out1T [n][256]
    gemm_bn<1><<<dim3(64, 4), 256, 24576 + 18432, stream>>>(
        wb1, xbT, g1, b1, m1, v1, nullptr, out1T, 1024, 1024);

    // Stage 2: offset conv, split-K x6 -> fp32 partials
    gemm_off<<<dim3(64, 6), 256, 0, stream>>>(wOffP, out1T, zbuf, offsP);

    // Stage 3a: deformable im2col (offsets reduced inline) -> ST [n][2304]
    sample_k<<<dim3(64, 2, 2), 256, 0, stream>>>(out1T, offsP, b_off, ST);

    // Stage 3b: deform GEMM, split-K x2 -> bf16 partials P
    gemm_bn<3><<<dim3(64, 4, 2), 256, 24576, stream>>>(
        wb2p, ST, nullptr, nullptr, nullptr, nullptr, nullptr, P, 2304, 1152);

    // Stage 3c: reduce + BN2 + ReLU -> o2T [n][256]
    reduce_bn<<<dim3(128, 4), 256, 0, stream>>>(P, g2, b2, m2, v2, o2T);

    // Stage 4: conv1x1 + BN3 + resid + ReLU -> fp32 out
    gemm_bn<2><<<dim3(64, 16), 256, 24576 + 64 * 132 * 4, stream>>>(
        wb3, o2T, g3, b3, m3, v3, x, out, 256, 256);
}

// Round 17
// 92.697 us; speedup vs baseline: 1.2443x; 1.2443x over previous
//
#include <hip/hip_runtime.h>
#include <hip/hip_bf16.h>

#define EPSV 1e-5f

typedef __attribute__((ext_vector_type(4))) float f32x4;
typedef __attribute__((ext_vector_type(8))) short bf16x8;
typedef unsigned short u16;
typedef unsigned int u32;

#define AS1(p) ((const __attribute__((address_space(1))) void*)(p))
#define AS3(p) ((__attribute__((address_space(3))) void*)(p))

__device__ __forceinline__ float bf2f(u16 u) {
    union { u32 i; float f; } x; x.i = ((u32)u) << 16; return x.f;
}
__device__ __forceinline__ u16 f2bf(float f) {
    __hip_bfloat16 h = __float2bfloat16(f);
    return *reinterpret_cast<u16*>(&h);
}

// ---------------------------------------------------------------------------
// Fused prep: weight conversions + 3x3 reorgs + zbuf. grid 649.
// ---------------------------------------------------------------------------
__global__ __launch_bounds__(256) void prep_all(
    const float* __restrict__ w1, const float* __restrict__ w3,
    const float* __restrict__ w_off, const float* __restrict__ w2,
    u16* __restrict__ wb1, u16* __restrict__ wb3,
    u16* __restrict__ wOffP, u16* __restrict__ wb2d,
    u16* __restrict__ zbuf)
{
    const int bz  = blockIdx.x;
    const int tid = threadIdx.x;
    if (bz < 512) {
        int i = bz * 256 + tid;
        const float* src; u16* dst; int j;
        if (i < 65536) { src = w1; dst = wb1; j = i; }
        else           { src = w3; dst = wb3; j = i - 65536; }
        float4 v = ((const float4*)src)[j];
        ushort4 o;
        o.x = f2bf(v.x); o.y = f2bf(v.y); o.z = f2bf(v.z); o.w = f2bf(v.w);
        ((ushort4*)dst)[j] = o;
        return;
    }
    const int bz1 = bz - 512;
    if (bz1 == 136) { ((u32*)zbuf)[tid] = 0; return; }
    if (bz1 < 64) {
#pragma unroll
        for (int k = 0; k < 9; k++) {
            float v = (bz1 < 18) ? w_off[((size_t)(bz1 * 256 + tid)) * 9 + k] : 0.f;
            wOffP[(size_t)bz1 * 2304 + k * 256 + tid] = f2bf(v);
        }
        return;
    }
    const int bz2 = bz1 - 64;         // 0..71 = kz*18 + set
    const int set = bz2 % 18;
    const int kz  = bz2 / 18;
    const int tap = set >> 1, hk = set & 1;
#pragma unroll
    for (int j = 0; j < 4; j++) {
        bf16x8 ov;
#pragma unroll
        for (int kk = 0; kk < 8; kk++) {
            const int ch = kz * 64 + hk * 32 + j * 8 + kk;
            ov[kk] = (short)f2bf(w2[((size_t)(tid * 256 + ch)) * 9 + tap]);
        }
        *(bf16x8*)(wb2d + ((size_t)(bz2 * 4 + j)) * 2048 + tid * 8) = ov;
    }
}

// ---------------------------------------------------------------------------
// x [2][1024][4096] fp32  ->  xbT [8192][1024] bf16
// ---------------------------------------------------------------------------
__global__ __launch_bounds__(256) void cvt_x_T(const float* __restrict__ x,
                                               u16* __restrict__ xbT) {
    __shared__ u16 tile[64][72];
    const int tid = threadIdx.x;
    const int hw0 = blockIdx.x << 6;
    const int c0  = blockIdx.y << 6;
    const int b   = blockIdx.z;
    const int cl  = tid >> 4;
    const int hwl = (tid & 15) << 2;
#pragma unroll
    for (int i = 0; i < 4; i++) {
        const int c = cl + i * 16;
        float4 v = *(const float4*)(x + (((size_t)(b * 1024 + c0 + c)) << 12) + hw0 + hwl);
        tile[hwl + 0][c] = f2bf(v.x);
        tile[hwl + 1][c] = f2bf(v.y);
        tile[hwl + 2][c] = f2bf(v.z);
        tile[hwl + 3][c] = f2bf(v.w);
    }
    __syncthreads();
    const int hw  = tid >> 2;
    const int seg = tid & 3;
    u16* dst = xbT + ((size_t)(b * 4096 + hw0 + hw)) * 1024 + c0 + seg * 16;
    const u16* src = &tile[hw][seg * 16];
#pragma unroll
    for (int q = 0; q < 2; q++)
        *(uint4*)(dst + q * 8) = *(const uint4*)(src + q * 8);
}

// ---------------------------------------------------------------------------
// Pipelined MFMA GEMM (64x128 tile, BK=32, 2-deep dbuf, counted vmcnt).
// MODE 1: BN+ReLU -> bf16 outT[8192][M] (stride 256), swizzled LDS transpose
// MODE 2: BN + resid + ReLU -> fp32 out [2][M][4096]
// ---------------------------------------------------------------------------
#define MFMA8(ASP, BSP)                                                          \
    do {                                                                         \
        bf16x8 a0 = *(const bf16x8*)(ASP);                                       \
        bf16x8 a1 = *(const bf16x8*)((ASP) + 512);                               \
        bf16x8 b0 = *(const bf16x8*)(BSP);                                       \
        bf16x8 b1 = *(const bf16x8*)((BSP) + 512);                               \
        bf16x8 b2 = *(const bf16x8*)((BSP) + 1024);                              \
        bf16x8 b3 = *(const bf16x8*)((BSP) + 1536);                              \
        acc[0][0] = __builtin_amdgcn_mfma_f32_16x16x32_bf16(a0, b0, acc[0][0], 0, 0, 0); \
        acc[0][1] = __builtin_amdgcn_mfma_f32_16x16x32_bf16(a0, b1, acc[0][1], 0, 0, 0); \
        acc[0][2] = __builtin_amdgcn_mfma_f32_16x16x32_bf16(a0, b2, acc[0][2], 0, 0, 0); \
        acc[0][3] = __builtin_amdgcn_mfma_f32_16x16x32_bf16(a0, b3, acc[0][3], 0, 0, 0); \
        acc[1][0] = __builtin_amdgcn_mfma_f32_16x16x32_bf16(a1, b0, acc[1][0], 0, 0, 0); \
        acc[1][1] = __builtin_amdgcn_mfma_f32_16x16x32_bf16(a1, b1, acc[1][1], 0, 0, 0); \
        acc[1][2] = __builtin_amdgcn_mfma_f32_16x16x32_bf16(a1, b2, acc[1][2], 0, 0, 0); \
        acc[1][3] = __builtin_amdgcn_mfma_f32_16x16x32_bf16(a1, b3, acc[1][3], 0, 0, 0); \
    } while (0)

#define WAIT_BAR()                                  \
    do {                                            \
        asm volatile("s_waitcnt vmcnt(3)" ::: "memory"); \
        __builtin_amdgcn_s_barrier();               \
        __builtin_amdgcn_sched_barrier(0);          \
    } while (0)

#define POST_BAR()                                  \
    do {                                            \
        __builtin_amdgcn_s_barrier();               \
        __builtin_amdgcn_sched_barrier(0);          \
    } while (0)

template<int MODE>
__global__ __launch_bounds__(256) void gemm_bn(
    const u16* __restrict__ A, const u16* __restrict__ BT,
    const float* __restrict__ g, const float* __restrict__ bb,
    const float* __restrict__ m, const float* __restrict__ v,
    const float* __restrict__ resid, void* __restrict__ out, int K, int Ksub)
{
    extern __shared__ char sm[];

    const int tid  = threadIdx.x;
    const int lane = tid & 63;
    const int wid  = tid >> 6;
    const int n0 = blockIdx.x << 7;
    const int m0 = blockIdx.y << 6;
    const int kBase = blockIdx.z * Ksub;
    const int wr = wid >> 1, wc = wid & 1;
    const int lr = lane & 15, kg = lane >> 4;

    f32x4 acc[2][4] = {};

    const int arow = tid >> 2, aseg = (tid & 3) << 3;
    const u16* aG  = A  + (size_t)(m0 + arow) * K + kBase + aseg;
    const u16* bG0 = BT + (size_t)(n0 + arow) * K + kBase + aseg;
    const u16* bG1 = BT + (size_t)(n0 + 64 + arow) * K + kBase + aseg;

    char* ldsA0  = sm + wid * 1024;
    char* ldsA1  = sm + 4096  + wid * 1024;
    char* ldsB00 = sm + 8192  + wid * 1024;
    char* ldsB01 = sm + 12288 + wid * 1024;
    char* ldsB10 = sm + 16384 + wid * 1024;
    char* ldsB11 = sm + 20480 + wid * 1024;

    const u16* Asp0 = (const u16*)(sm)         + (wr * 32 + lr) * 32 + kg * 8;
    const u16* Asp1 = (const u16*)(sm + 4096)  + (wr * 32 + lr) * 32 + kg * 8;
    const u16* Bsp0 = (const u16*)(sm + 8192)  + (wc * 64 + lr) * 32 + kg * 8;
    const u16* Bsp1 = (const u16*)(sm + 16384) + (wc * 64 + lr) * 32 + kg * 8;

    // BN params preloaded + fenced BEFORE the pipeline (in-loop VMEM == staging)
    float sc[2][4], tc[2][4];
#pragma unroll
    for (int mm = 0; mm < 2; mm++)
#pragma unroll
        for (int r = 0; r < 4; r++) {
            const int o = m0 + wr * 32 + mm * 16 + kg * 4 + r;
            const float s = g[o] * rsqrtf(v[o] + EPSV);
            sc[mm][r] = s;
            tc[mm][r] = bb[o] - m[o] * s;
        }
    asm volatile("s_waitcnt vmcnt(0) lgkmcnt(0)" ::: "memory");
    __builtin_amdgcn_sched_barrier(0);

#define ISSUE_G(LA, LB0, LB1, kt)                                                  \
    do {                                                                           \
        __builtin_amdgcn_global_load_lds(AS1(aG + (kt)),  AS3(LA),  16, 0, 0);     \
        __builtin_amdgcn_global_load_lds(AS1(bG0 + (kt)), AS3(LB0), 16, 0, 0);     \
        __builtin_amdgcn_global_load_lds(AS1(bG1 + (kt)), AS3(LB1), 16, 0, 0);     \
    } while (0)

    const int nT = Ksub >> 5;
    ISSUE_G(ldsA0, ldsB00, ldsB01, 0);
    ISSUE_G(ldsA1, ldsB10, ldsB11, 32);

    for (int t = 0; t < nT; t += 2) {
        WAIT_BAR();
        MFMA8(Asp0, Bsp0);
        POST_BAR();
        { const int kn = (t + 2 < nT ? t + 2 : t) << 5;
          ISSUE_G(ldsA0, ldsB00, ldsB01, kn); }
        WAIT_BAR();
        MFMA8(Asp1, Bsp1);
        POST_BAR();
        { const int kn = (t + 3 < nT ? t + 3 : t + 1) << 5;
          ISSUE_G(ldsA1, ldsB10, ldsB11, kn); }
    }
#undef ISSUE_G

    if (MODE == 1) {
        u32* T32 = (u32*)(sm + 24576);
#pragma unroll
        for (int mm = 0; mm < 2; mm++) {
            const int ol = wr * 32 + mm * 16 + kg * 4;
            const int cw0 = ol >> 1;
#pragma unroll
            for (int j = 0; j < 4; j++) {
                const int nl = wc * 64 + j * 16 + lr;
                const int sw = (nl >> 3) & 3;
                float v0 = acc[mm][j][0] * sc[mm][0] + tc[mm][0];
                float v1 = acc[mm][j][1] * sc[mm][1] + tc[mm][1];
                float v2 = acc[mm][j][2] * sc[mm][2] + tc[mm][2];
                float v3 = acc[mm][j][3] * sc[mm][3] + tc[mm][3];
                v0 = v0 > 0.f ? v0 : 0.f; v1 = v1 > 0.f ? v1 : 0.f;
                v2 = v2 > 0.f ? v2 : 0.f; v3 = v3 > 0.f ? v3 : 0.f;
                uint2 pw;
                pw.x = (u32)f2bf(v0) | ((u32)f2bf(v1) << 16);
                pw.y = (u32)f2bf(v2) | ((u32)f2bf(v3) << 16);
                *(uint2*)&T32[nl * 36 + (cw0 ^ (sw << 2))] = pw;
            }
        }
        __syncthreads();
        const int nl = tid >> 1, half = tid & 1;
        const int sw = (nl >> 3) & 3;
        u16* dst = (u16*)out + (size_t)(n0 + nl) * 256 + m0 + half * 32;
#pragma unroll
        for (int q = 0; q < 4; q++) {
            uint4 val = *(const uint4*)&T32[nl * 36 + ((half * 16 + q * 4) ^ (sw << 2))];
            *(uint4*)(dst + q * 8) = val;
        }
    } else {
        float* T = (float*)(sm + 24576);   // [64][132]
#pragma unroll
        for (int mm = 0; mm < 2; mm++) {
            const int ol = wr * 32 + mm * 16 + kg * 4;
#pragma unroll
            for (int j = 0; j < 4; j++) {
                const int nl = wc * 64 + j * 16 + lr;
#pragma unroll
                for (int r = 0; r < 4; r++)
                    T[(ol + r) * 132 + nl] = acc[mm][j][r] * sc[mm][r] + tc[mm][r];
            }
        }
        __syncthreads();
        float* O = (float*)out;
        for (int idx = tid; idx < 2048; idx += 256) {
            const int ol  = idx >> 5;
            const int nl4 = (idx & 31) << 2;
            const int n = n0 + nl4;
            const size_t gidx = ((size_t)(n >> 12) << 22) + ((size_t)(m0 + ol) << 12) + (n & 4095);
            float4 rv = *(const float4*)(resid + gidx);
            float4 ov;
            ov.x = T[ol * 132 + nl4 + 0] + rv.x;
            ov.y = T[ol * 132 + nl4 + 1] + rv.y;
            ov.z = T[ol * 132 + nl4 + 2] + rv.z;
            ov.w = T[ol * 132 + nl4 + 3] + rv.w;
            ov.x = ov.x > 0.f ? ov.x : 0.f;
            ov.y = ov.y > 0.f ? ov.y : 0.f;
            ov.z = ov.z > 0.f ? ov.z : 0.f;
            ov.w = ov.w > 0.f ? ov.w : 0.f;
            *(float4*)(O + gidx) = ov;
        }
    }
}

// ---------------------------------------------------------------------------
// Offset conv: split-K x6 implicit-im2col MFMA GEMM, 2-deep pipeline.
// ---------------------------------------------------------------------------
__global__ __launch_bounds__(256) void gemm_off(
    const u16* __restrict__ A,      // [64][2304] (rows >=18 zero)
    const u16* __restrict__ out1T,  // [8192][256]
    const u16* __restrict__ zbuf,
    float* __restrict__ offsP)      // [6][2][18][4096]
{
    __shared__ char sm[24576];

    const int tid  = threadIdx.x;
    const int lane = tid & 63;
    const int wid  = tid >> 6;
    const int n0 = blockIdx.x << 7;
    const int kz = blockIdx.y;
    const int wr = wid >> 1, wc = wid & 1;
    const int lr = lane & 15, kg = lane >> 4;

    f32x4 acc[2][4] = {};

    const int arow = tid >> 2, aseg = (tid & 3) << 3;
    const u16* aG = A + (size_t)arow * 2304 + aseg;
    const int nB0 = n0 + arow, nB1 = n0 + 64 + arow;
    const int y0r = (nB0 & 4095) >> 6, x0r = nB0 & 63;
    const int y1r = (nB1 & 4095) >> 6, x1r = nB1 & 63;

    char* ldsA0  = sm + wid * 1024;
    char* ldsA1  = sm + 4096  + wid * 1024;
    char* ldsB00 = sm + 8192  + wid * 1024;
    char* ldsB01 = sm + 12288 + wid * 1024;
    char* ldsB10 = sm + 16384 + wid * 1024;
    char* ldsB11 = sm + 20480 + wid * 1024;

    const u16* Asp0 = (const u16*)(sm)         + (wr * 32 + lr) * 32 + kg * 8;
    const u16* Asp1 = (const u16*)(sm + 4096)  + (wr * 32 + lr) * 32 + kg * 8;
    const u16* Bsp0 = (const u16*)(sm + 8192)  + (wc * 64 + lr) * 32 + kg * 8;
    const u16* Bsp1 = (const u16*)(sm + 16384) + (wc * 64 + lr) * 32 + kg * 8;

#define ISSUE_O(LA, LB0, LB1, kt)                                                  \
    do {                                                                           \
        const int tap = (kt) >> 8, c0 = (kt) & 255;                                \
        const int dy = tap / 3 - 1, dx = tap % 3 - 1;                              \
        const int sh = dy * 64 + dx;                                               \
        const bool vv0 = ((unsigned)(y0r + dy) < 64u) && ((unsigned)(x0r + dx) < 64u); \
        const bool vv1 = ((unsigned)(y1r + dy) < 64u) && ((unsigned)(x1r + dx) < 64u); \
        const u16* s0 = vv0 ? out1T + (size_t)(nB0 + sh) * 256 + c0 + aseg : zbuf + aseg; \
        const u16* s1 = vv1 ? out1T + (size_t)(nB1 + sh) * 256 + c0 + aseg : zbuf + aseg; \
        __builtin_amdgcn_global_load_lds(AS1(aG + (kt)), AS3(LA),  16, 0, 0);      \
        __builtin_amdgcn_global_load_lds(AS1(s0),        AS3(LB0), 16, 0, 0);      \
        __builtin_amdgcn_global_load_lds(AS1(s1),        AS3(LB1), 16, 0, 0);      \
    } while (0)

    const int kBase = kz * 384;
    ISSUE_O(ldsA0, ldsB00, ldsB01, kBase);
    ISSUE_O(ldsA1, ldsB10, ldsB11, kBase + 32);

    for (int t = 0; t < 12; t += 2) {
        WAIT_BAR();
        MFMA8(Asp0, Bsp0);
        POST_BAR();
        { const int kn = kBase + ((t + 2 < 12 ? t + 2 : t) << 5);
          ISSUE_O(ldsA0, ldsB00, ldsB01, kn); }
        WAIT_BAR();
        MFMA8(Asp1, Bsp1);
        POST_BAR();
        { const int kn = kBase + ((t + 3 < 12 ? t + 3 : t + 1) << 5);
          ISSUE_O(ldsA1, ldsB10, ldsB11, kn); }
    }
#undef ISSUE_O

    asm volatile("s_waitcnt vmcnt(0)" ::: "memory");

#pragma unroll
    for (int mm = 0; mm < 2; mm++)
#pragma unroll
        for (int r = 0; r < 4; r++) {
            const int o = wr * 32 + mm * 16 + kg * 4 + r;
            if (o < 18) {
#pragma unroll
                for (int j = 0; j < 4; j++) {
                    const int n = n0 + wc * 64 + j * 16 + lr;
                    offsP[(size_t)kz * 147456 +
                          (((size_t)((n >> 12) * 18 + o)) << 12) + (n & 4095)] =
                        acc[mm][j][r];
                }
            }
        }
}

// ---------------------------------------------------------------------------
// Fused deformable-sampling MFMA GEMM -> bf16 partials P[kz][256][8192].
// Tile 256m x 64n, BK=32, grid (128 n-tiles, 4 kz).
// A fragments loaded DIRECTLY global->reg (wb2d layout == fragment layout);
// B built in-register from 4 bilinear corners and ds_write-staged. Offset
// partials summed inline in the geometry pass. One lgkmcnt(0)+barrier per
// phase; no manual vmcnt (replay-proven pattern).
// LDS: B0@0 B1@4160 s_ofs@8320 s_w@17536 (total 26752)
// ---------------------------------------------------------------------------
__global__ __launch_bounds__(256) void gemm_def(
    const u16* __restrict__ wb2d,   // [4][18][4][256][8]
    const u16* __restrict__ out1T,  // [8192][256]
    const float* __restrict__ offsP,// [6][2][18][4096]
    const float* __restrict__ b_off,
    u16* __restrict__ P)            // [4][256][8192] bf16
{
    extern __shared__ char sm[];
    char*   ldsB0 = sm;
    char*   ldsB1 = sm + 4160;
    int4*   s_ofs = (int4*)(sm + 8320);
    float4* s_w   = (float4*)(sm + 17536);

    const int tid  = threadIdx.x;
    const int lane = tid & 63;
    const int wid  = tid >> 6;
    const int n0 = blockIdx.x << 6;
    const int kz = blockIdx.y;
    const int b  = n0 >> 12;
    const int h  = (n0 >> 6) & 63;
    const int lr = lane & 15, kg = lane >> 4;

    // ---- geometry: 64 rows x 9 taps; offset partial-sum folded in ----
    for (int p = tid; p < 576; p += 256) {
        const int t   = p >> 6;        // tap (coalesced load index)
        const int nl_ = p & 63;        // row
        const size_t iy = (((size_t)(b * 18 + 2 * t)) << 12) + (h << 6) + nl_;
        float dy = b_off[2 * t], dx = b_off[2 * t + 1];
#pragma unroll
        for (int kzz = 0; kzz < 6; kzz++) {
            dy += offsP[(size_t)kzz * 147456 + iy];
            dx += offsP[(size_t)kzz * 147456 + iy + 4096];
        }
        const float py = (float)h + (float)(t / 3 - 1) + dy;
        const float px = (float)nl_ + (float)(t % 3 - 1) + dx;
        const float y0f = floorf(py), x0f = floorf(px);
        const int y0 = (int)y0f, x0 = (int)x0f;
        const float wy1 = py - y0f, wx1 = px - x0f;
        const float wy0 = 1.f - wy1, wx0 = 1.f - wx1;
        const int y1 = y0 + 1, x1 = x0 + 1;
        const bool vy0 = (y0 >= 0) && (y0 < 64);
        const bool vy1 = (y1 >= 0) && (y1 < 64);
        const bool vx0 = (x0 >= 0) && (x0 < 64);
        const bool vx1 = (x1 >= 0) && (x1 < 64);
        const int cy0 = min(max(y0, 0), 63), cy1 = min(max(y1, 0), 63);
        const int cx0 = min(max(x0, 0), 63), cx1 = min(max(x1, 0), 63);
        const int rb = b << 12;
        int4 o4; float4 w4;
        o4.x = (rb + (cy0 << 6) + cx0) << 9;  w4.x = wy0 * wx0 * ((vy0 && vx0) ? 1.f : 0.f);
        o4.y = (rb + (cy0 << 6) + cx1) << 9;  w4.y = wy0 * wx1 * ((vy0 && vx1) ? 1.f : 0.f);
        o4.z = (rb + (cy1 << 6) + cx0) << 9;  w4.z = wy1 * wx0 * ((vy1 && vx0) ? 1.f : 0.f);
        o4.w = (rb + (cy1 << 6) + cx1) << 9;  w4.w = wy1 * wx1 * ((vy1 && vx1) ? 1.f : 0.f);
        s_ofs[nl_ * 9 + t] = o4; s_w[nl_ * 9 + t] = w4;
    }
    __syncthreads();

    const int nl = tid >> 2;                 // B row (n-local)
    const int q  = tid & 3;                  // k-quarter within BK=32
    const u16* aSet  = wb2d + (size_t)(kz * 18) * 8192 + kg * 2048
                            + (wid * 64 + lr) * 8;   // per-set: + set*8192
    const char* o1B = (const char*)out1T;
    const int cbQ = kz * 128 + q * 16;       // corner byte offset (per-quarter)

    f32x4 acc[4][4] = {};
    bf16x8 av0[4], av1[4], cr0[4], cr1[4];

#define PWC(p_) ((p_) < 18 ? (p_) : 17)

#define LOADA(RI, pt_)                                                             \
    do {                                                                           \
        const u16* ag_ = aSet + (size_t)(pt_) * 8192;                              \
        av##RI[0] = *(const bf16x8*)(ag_);                                         \
        av##RI[1] = *(const bf16x8*)(ag_ + 128);                                   \
        av##RI[2] = *(const bf16x8*)(ag_ + 256);                                   \
        av##RI[3] = *(const bf16x8*)(ag_ + 384);                                   \
    } while (0)

#define LOADC(RI, pt_)                                                             \
    do {                                                                           \
        const int tap_ = (pt_) >> 1, hk_ = (pt_) & 1;                              \
        const int4 o4_ = s_ofs[nl * 9 + tap_];                                     \
        const int cb_ = cbQ + hk_ * 64;                                            \
        cr##RI[0] = *(const bf16x8*)(o1B + o4_.x + cb_);                           \
        cr##RI[1] = *(const bf16x8*)(o1B + o4_.y + cb_);                           \
        cr##RI[2] = *(const bf16x8*)(o1B + o4_.z + cb_);                           \
        cr##RI[3] = *(const bf16x8*)(o1B + o4_.w + cb_);                           \
    } while (0)

#define PACKB(RI, LB, pw_)                                                         \
    do {                                                                           \
        const float4 w4_ = s_w[nl * 9 + ((pw_) >> 1)];                             \
        bf16x8 pk_;                                                                \
        _Pragma("unroll")                                                          \
        for (int i_ = 0; i_ < 8; i_++) {                                           \
            const float f_ = w4_.x * bf2f((u16)cr##RI[0][i_])                      \
                           + w4_.y * bf2f((u16)cr##RI[1][i_])                      \
                           + w4_.z * bf2f((u16)cr##RI[2][i_])                      \
                           + w4_.w * bf2f((u16)cr##RI[3][i_]);                     \
            pk_[i_] = (short)f2bf(f_);                                             \
        }                                                                          \
        *(bf16x8*)((LB) + q * 1040 + nl * 16) = pk_;                               \
    } while (0)

#define MFMA16(AV, LB)                                                             \
    do {                                                                           \
        bf16x8 bv0 = *(const bf16x8*)((LB) + kg * 1040 + ( 0 + lr) * 16);          \
        bf16x8 bv1 = *(const bf16x8*)((LB) + kg * 1040 + (16 + lr) * 16);          \
        bf16x8 bv2 = *(const bf16x8*)((LB) + kg * 1040 + (32 + lr) * 16);          \
        bf16x8 bv3 = *(const bf16x8*)((LB) + kg * 1040 + (48 + lr) * 16);          \
        acc[0][0] = __builtin_amdgcn_mfma_f32_16x16x32_bf16(AV[0], bv0, acc[0][0], 0, 0, 0); \
        acc[0][1] = __builtin_amdgcn_mfma_f32_16x16x32_bf16(AV[0], bv1, acc[0][1], 0, 0, 0); \
        acc[0][2] = __builtin_amdgcn_mfma_f32_16x16x32_bf16(AV[0], bv2, acc[0][2], 0, 0, 0); \
        acc[0][3] = __builtin_amdgcn_mfma_f32_16x16x32_bf16(AV[0], bv3, acc[0][3], 0, 0, 0); \
        acc[1][0] = __builtin_amdgcn_mfma_f32_16x16x32_bf16(AV[1], bv0, acc[1][0], 0, 0, 0); \
        acc[1][1] = __builtin_amdgcn_mfma_f32_16x16x32_bf16(AV[1], bv1, acc[1][1], 0, 0, 0); \
        acc[1][2] = __builtin_amdgcn_mfma_f32_16x16x32_bf16(AV[1], bv2, acc[1][2], 0, 0, 0); \
        acc[1][3] = __builtin_amdgcn_mfma_f32_16x16x32_bf16(AV[1], bv3, acc[1][3], 0, 0, 0); \
        acc[2][0] = __builtin_amdgcn_mfma_f32_16x16x32_bf16(AV[2], bv0, acc[2][0], 0, 0, 0); \
        acc[2][1] = __builtin_amdgcn_mfma_f32_16x16x32_bf16(AV[2], bv1, acc[2][1], 0, 0, 0); \
        acc[2][2] = __builtin_amdgcn_mfma_f32_16x16x32_bf16(AV[2], bv2, acc[2][2], 0, 0, 0); \
        acc[2][3] = __builtin_amdgcn_mfma_f32_16x16x32_bf16(AV[2], bv3, acc[2][3], 0, 0, 0); \
        acc[3][0] = __builtin_amdgcn_mfma_f32_16x16x32_bf16(AV[3], bv0, acc[3][0], 0, 0, 0); \
        acc[3][1] = __builtin_amdgcn_mfma_f32_16x16x32_bf16(AV[3], bv1, acc[3][1], 0, 0, 0); \
        acc[3][2] = __builtin_amdgcn_mfma_f32_16x16x32_bf16(AV[3], bv2, acc[3][2], 0, 0, 0); \
        acc[3][3] = __builtin_amdgcn_mfma_f32_16x16x32_bf16(AV[3], bv3, acc[3][3], 0, 0, 0); \
    } while (0)

#define END_BAR()                                   \
    do {                                            \
        asm volatile("s_waitcnt lgkmcnt(0)" ::: "memory"); \
        __builtin_amdgcn_s_barrier();               \
        __builtin_amdgcn_sched_barrier(0);          \
    } while (0)

    // prologue
    LOADC(0, 0); LOADA(0, 0);
    LOADC(1, 1); LOADA(1, 1);
    PACKB(0, ldsB0, 0);
    LOADC(0, 2);
    END_BAR();

    for (int t = 0; t < 18; t += 2) {
        PACKB(1, ldsB1, PWC(t + 1));
        LOADC(1, PWC(t + 3));
        MFMA16(av0, ldsB0);
        LOADA(0, PWC(t + 2));
        END_BAR();
        PACKB(0, ldsB0, PWC(t + 2));
        LOADC(0, PWC(t + 4));
        MFMA16(av1, ldsB1);
        LOADA(1, PWC(t + 3));
        END_BAR();
    }
#undef END_BAR
#undef MFMA16
#undef PACKB
#undef LOADC
#undef LOADA
#undef PWC

    u16* Pk = P + (size_t)kz * 2097152;
#pragma unroll
    for (int mf = 0; mf < 4; mf++)
#pragma unroll
        for (int r = 0; r < 4; r++) {
            const int o = wid * 64 + mf * 16 + kg * 4 + r;
#pragma unroll
            for (int nf = 0; nf < 4; nf++) {
                const int n = n0 + nf * 16 + lr;
                Pk[((size_t)o << 13) + n] = f2bf(acc[mf][nf][r]);
            }
        }
}

// ---------------------------------------------------------------------------
// Split-K reduce for the deform GEMM: o2T[n][m] = relu(bn(P0+P1+P2+P3)).
// P is bf16; accumulate in fp32.
// ---------------------------------------------------------------------------
__global__ __launch_bounds__(256) void reduce_bn(
    const u16* __restrict__ P,      // [4][256][8192] bf16
    const float* __restrict__ g, const float* __restrict__ bb,
    const float* __restrict__ m, const float* __restrict__ v,
    u16* __restrict__ o2T)          // [8192][256]
{
    __shared__ u16 tile[64][72];
    const int tid = threadIdx.x;
    const int n0 = blockIdx.x << 6;
    const int m0 = blockIdx.y << 6;

    const int ml = tid >> 2;
    const int ns = (tid & 3) << 4;
    const int o = m0 + ml;
    const float s = g[o] * rsqrtf(v[o] + EPSV);
    const float tcv = bb[o] - m[o] * s;
    const size_t base = ((size_t)o << 13) + n0 + ns;
#pragma unroll
    for (int qq = 0; qq < 2; qq++) {
        bf16x8 a = *(const bf16x8*)(P + base + qq * 8);
        bf16x8 b = *(const bf16x8*)(P + 2097152 + base + qq * 8);
        bf16x8 c = *(const bf16x8*)(P + 2 * 2097152 + base + qq * 8);
        bf16x8 d = *(const bf16x8*)(P + 3 * 2097152 + base + qq * 8);
#pragma unroll
        for (int i = 0; i < 8; i++) {
            float f = (bf2f((u16)a[i]) + bf2f((u16)b[i])
                     + bf2f((u16)c[i]) + bf2f((u16)d[i])) * s + tcv;
            f = f > 0.f ? f : 0.f;
            tile[ns + qq * 8 + i][ml] = f2bf(f);
        }
    }
    __syncthreads();
    const int nl = tid >> 2, seg = tid & 3;
    u16* dst = o2T + (size_t)(n0 + nl) * 256 + m0 + seg * 16;
    const u16* src = &tile[nl][seg * 16];
#pragma unroll
    for (int qq = 0; qq < 2; qq++)
        *(uint4*)(dst + qq * 8) = *(const uint4*)(src + qq * 8);
}

// ---------------------------------------------------------------------------
extern "C" void kernel_launch(void* const* d_in, const int* in_sizes, int n_in,
                              void* d_out, int out_size, void* d_ws, size_t ws_size,
                              hipStream_t stream) {
    const float* x     = (const float*)d_in[0];
    const float* w1    = (const float*)d_in[1];
    const float* g1    = (const float*)d_in[2];
    const float* b1    = (const float*)d_in[3];
    const float* m1    = (const float*)d_in[4];
    const float* v1    = (const float*)d_in[5];
    const float* w_off = (const float*)d_in[6];
    const float* b_off = (const float*)d_in[7];
    const float* w2    = (const float*)d_in[8];
    const float* g2    = (const float*)d_in[9];
    const float* b2    = (const float*)d_in[10];
    const float* m2    = (const float*)d_in[11];
    const float* v2    = (const float*)d_in[12];
    const float* w3    = (const float*)d_in[13];
    const float* g3    = (const float*)d_in[14];
    const float* b3    = (const float*)d_in[15];
    const float* m3    = (const float*)d_in[16];
    const float* v3    = (const float*)d_in[17];
    float* out = (float*)d_out;

    char* ws = (char*)d_ws;
    u16*  xbT   = (u16*)ws;   ws += (size_t)8192 * 1024 * 2;
    u16*  wb1   = (u16*)ws;   ws += (size_t)256 * 1024 * 2;
    u16*  wb3   = (u16*)ws;   ws += (size_t)1024 * 256 * 2;
    u16*  wOffP = (u16*)ws;   ws += (size_t)64 * 2304 * 2;
    u16*  wb2d  = (u16*)ws;   ws += (size_t)72 * 8192 * 2;
    u16*  zbuf  = (u16*)ws;   ws += (size_t)512 * 2;
    u16*  out1T = (u16*)ws;   ws += (size_t)8192 * 256 * 2;
    float* offsP = (float*)ws; ws += (size_t)6 * 147456 * 4;
    u16*  o2T   = (u16*)ws;   ws += (size_t)8192 * 256 * 2;
    u16*  P     = (u16*)ws;   ws += (size_t)4 * 2097152 * 2;   // 16.8 MB bf16

    prep_all<<<dim3(649), 256, 0, stream>>>(w1, w3, w_off, w2,
                                            wb1, wb3, wOffP, wb2d, zbuf);
    cvt_x_T<<<dim3(64, 16, 2), 256, 0, stream>>>(x, xbT);

    // Stage 1: conv1x1 + BN1 + ReLU -> out1T [n][256]
    gemm_bn<1><<<dim3(64, 4), 256, 24576 + 18432, stream>>>(
        wb1, xbT, g1, b1, m1, v1, nullptr, out1T, 1024, 1024);

    // Stage 2: offset conv, split-K x6 -> fp32 partials
    gemm_off<<<dim3(64, 6), 256, 0, stream>>>(wOffP, out1T, zbuf, offsP);

    // Stage 3: fused deformable-sampling GEMM -> bf16 partials P
    gemm_def<<<dim3(128, 4), 256, 26752, stream>>>(wb2d, out1T, offsP, b_off, P);

    // Stage 3c: reduce + BN2 + ReLU -> o2T [n][256]
    reduce_bn<<<dim3(128, 4), 256, 0, stream>>>(P, g2, b2, m2, v2, o2T);

    // Stage 4: conv1x1 + BN3 + resid + ReLU -> fp32 out
    gemm_bn<2><<<dim3(64, 16), 256, 24576 + 64 * 132 * 4, stream>>>(
        wb3, o2T, g3, b3, m3, v3, x, out, 256, 256);
}